// Round 4
// baseline (168.608 us; speedup 1.0000x reference)
//
#include <hip/hip_runtime.h>
#include <math.h>

// SupCR loss, MI355X. Round 12:
//  - row_kernel tail: round-11's f64 atomicAdd (CAS retry convoy across 1024
//    co-resident blocks; +25 us total, row dispatch 48 us) replaced by plain
//    rowval[pr] store + __threadfence + native int fetch_add(ACQ_REL, agent);
//    last block reduces 1024 doubles via agent-scope atomic loads (coherent
//    across XCDs) into LDS reused from dead key[].
//  - scans: prefix+suffix wave scans fused behind ONE barrier per row
//    (was two). Same math.
//  - GEMM: round-8 structure (128x64 reg-staged, 272 lower-band tiles).
//  - prep: fused bf16 split/norms + parallel rank sort; zeroes cnt.

#define NN 2048      // N = B*V
#define BB 1024      // B
#define DD 512       // D
#define NT 256
#define NEGINF (-INFINITY)
#define CS 64.0f     // exponent pre-scale bias

typedef short s16x8 __attribute__((ext_vector_type(8)));
typedef float f32x4 __attribute__((ext_vector_type(4)));

// row i of the virtual cf matrix lives at F + ((i%B)*2 + i/B)*D
__device__ __forceinline__ const float* cf_row(const float* F, int i) {
    return F + ((size_t)(i & (BB - 1)) * 2 + (size_t)(i >> 10)) * DD;
}

__device__ __forceinline__ unsigned bf_rne(float x) {
    const unsigned u = __float_as_uint(x);
    return (u + 0x7FFFu + ((u >> 16) & 1u)) >> 16;
}
__device__ __forceinline__ float bf_val(unsigned h) {
    return __uint_as_float(h << 16);
}

// ---------------- kernel 0: fused prep (blocks 0..255) + rank sort (256,257) ----
__global__ __launch_bounds__(512) void prep_sort_kernel(const float* __restrict__ F,
                                                        const float* __restrict__ labels,
                                                        ushort* __restrict__ Ahi,
                                                        ushort* __restrict__ Alo,
                                                        float* __restrict__ sq,
                                                        float* __restrict__ slab,
                                                        int* __restrict__ sj,
                                                        int* __restrict__ cnt) {
    __shared__ float lab[BB];
    const int blk = blockIdx.x;
    const int t = threadIdx.x;

    if (blk < 256) {
        // ---- prep: 8 rows per block, one row per wave ----
        const int lane = t & 63;
        const int w = t >> 6;
        const int i = blk * 8 + w;
        const float* src = cf_row(F, i);
        const float4 v0 = reinterpret_cast<const float4*>(src)[lane];
        const float4 v1 = reinterpret_cast<const float4*>(src)[lane + 64];
        float ss = v0.x * v0.x + v0.y * v0.y + v0.z * v0.z + v0.w * v0.w
                 + v1.x * v1.x + v1.y * v1.y + v1.z * v1.z + v1.w * v1.w;
        #pragma unroll
        for (int st = 32; st > 0; st >>= 1) ss += __shfl_down(ss, st);
        if (lane == 0) sq[i] = ss;

        const float a[8] = {v0.x, v0.y, v0.z, v0.w, v1.x, v1.y, v1.z, v1.w};
        ushort h[8], l[8];
        #pragma unroll
        for (int e = 0; e < 8; ++e) {
            const unsigned hb = bf_rne(a[e]);
            h[e] = (ushort)hb;
            l[e] = (ushort)bf_rne(a[e] - bf_val(hb));
        }
        const size_t base = (size_t)i * DD;
        *reinterpret_cast<ushort4*>(&Ahi[base + lane * 4])       = make_ushort4(h[0], h[1], h[2], h[3]);
        *reinterpret_cast<ushort4*>(&Ahi[base + 256 + lane * 4]) = make_ushort4(h[4], h[5], h[6], h[7]);
        *reinterpret_cast<ushort4*>(&Alo[base + lane * 4])       = make_ushort4(l[0], l[1], l[2], l[3]);
        *reinterpret_cast<ushort4*>(&Alo[base + 256 + lane * 4]) = make_ushort4(l[4], l[5], l[6], l[7]);
    } else {
        // ---- rank sort: block 256 -> elements 0..511, block 257 -> 512..1023 ----
        if (blk == 257 && t == 0) { *cnt = 0; }
        lab[t] = labels[t];
        lab[t + 512] = labels[t + 512];
        __syncthreads();
        const int e = (blk - 256) * 512 + t;
        const float li = lab[e];
        int rank = 0;
        const float4* l4 = reinterpret_cast<const float4*>(lab);
        #pragma unroll 4
        for (int j = 0; j < BB / 4; ++j) {
            const float4 v = l4[j];
            const int j0 = j * 4;
            rank += (v.x < li) || (v.x == li && (j0 + 0) < e);
            rank += (v.y < li) || (v.y == li && (j0 + 1) < e);
            rank += (v.z < li) || (v.z == li && (j0 + 2) < e);
            rank += (v.w < li) || (v.w == li && (j0 + 3) < e);
        }
        slab[2 * rank]     = li;
        slab[2 * rank + 1] = li;
        sj[2 * rank]     = e;
        sj[2 * rank + 1] = e + BB;
    }
}

// ---------------- kernel 1: MFMA dist, symmetric (lower tiles only) ---------
#define TM 128
#define TN 64
#define TK 32
__global__ __launch_bounds__(256) void gemm_dist_kernel(const ushort* __restrict__ Ahi,
                                                        const ushort* __restrict__ Alo,
                                                        const float* __restrict__ sq,
                                                        const int* __restrict__ sj,
                                                        float* __restrict__ distp) {
    __shared__ ushort Ah[4][TM][8];
    __shared__ ushort Al[4][TM][8];
    __shared__ ushort Bh[4][TN][8];
    __shared__ ushort Bl[4][TN][8];
    __shared__ int   sjcA[TM];
    __shared__ int   sjcB[TN];
    __shared__ float sqA[TM];
    __shared__ float sqB[TN];

    const int t = threadIdx.x;
    const int lane = t & 63;
    const int w = t >> 6;

    // tile id -> (by, bx) over the lower-triangular band: C(by)=by*(by+1)
    const int id = blockIdx.x;
    int by = (int)((__fsqrt_rn(4.0f * (float)id + 1.0f) - 1.0f) * 0.5f);
    while ((by + 1) * (by + 2) <= id) ++by;
    while (by * (by + 1) > id) --by;
    const int bx = id - by * (by + 1);          // 0 .. 2*by+1
    const int row0 = by * TM;
    const int col0 = bx * TN;
    const bool below = (bx < 2 * by);           // strictly left of diag square

    if (t < TM) {
        const int s = sj[row0 + t];
        sjcA[t] = s; sqA[t] = sq[s];
    } else if (t < TM + TN) {
        const int u = t - TM;
        const int s = sj[col0 + u];
        sjcB[u] = s; sqB[u] = sq[s];
    }
    __syncthreads();
    const int rr = t >> 2;
    const int cq = t & 3;
    const size_t gA0 = (size_t)sjcA[rr] * DD + cq * 8;
    const size_t gA1 = (size_t)sjcA[64 + rr] * DD + cq * 8;
    const size_t gB0 = (size_t)sjcB[rr] * DD + cq * 8;

    f32x4 acc[2][4] = {};
    const int m = lane & 15;
    const int q = lane >> 4;

    for (int kt = 0; kt < DD / TK; ++kt) {
        __syncthreads();
        const size_t ko = (size_t)kt * TK;
        *reinterpret_cast<int4*>(&Ah[cq][rr][0])      = *reinterpret_cast<const int4*>(&Ahi[gA0 + ko]);
        *reinterpret_cast<int4*>(&Al[cq][rr][0])      = *reinterpret_cast<const int4*>(&Alo[gA0 + ko]);
        *reinterpret_cast<int4*>(&Ah[cq][64 + rr][0]) = *reinterpret_cast<const int4*>(&Ahi[gA1 + ko]);
        *reinterpret_cast<int4*>(&Al[cq][64 + rr][0]) = *reinterpret_cast<const int4*>(&Alo[gA1 + ko]);
        *reinterpret_cast<int4*>(&Bh[cq][rr][0])      = *reinterpret_cast<const int4*>(&Ahi[gB0 + ko]);
        *reinterpret_cast<int4*>(&Bl[cq][rr][0])      = *reinterpret_cast<const int4*>(&Alo[gB0 + ko]);
        __syncthreads();

        s16x8 fah[2], fal[2], fbh[4], fbl[4];
        #pragma unroll
        for (int mt = 0; mt < 2; ++mt) {
            fah[mt] = *reinterpret_cast<const s16x8*>(&Ah[q][w * 32 + mt * 16 + m][0]);
            fal[mt] = *reinterpret_cast<const s16x8*>(&Al[q][w * 32 + mt * 16 + m][0]);
        }
        #pragma unroll
        for (int nt = 0; nt < 4; ++nt) {
            fbh[nt] = *reinterpret_cast<const s16x8*>(&Bh[q][nt * 16 + m][0]);
            fbl[nt] = *reinterpret_cast<const s16x8*>(&Bl[q][nt * 16 + m][0]);
        }
        #pragma unroll
        for (int mt = 0; mt < 2; ++mt)
            #pragma unroll
            for (int nt = 0; nt < 4; ++nt) {
                acc[mt][nt] = __builtin_amdgcn_mfma_f32_16x16x32_bf16(fah[mt], fbh[nt], acc[mt][nt], 0, 0, 0);
                acc[mt][nt] = __builtin_amdgcn_mfma_f32_16x16x32_bf16(fah[mt], fbl[nt], acc[mt][nt], 0, 0, 0);
                acc[mt][nt] = __builtin_amdgcn_mfma_f32_16x16x32_bf16(fal[mt], fbh[nt], acc[mt][nt], 0, 0, 0);
            }
    }

    #pragma unroll
    for (int mt = 0; mt < 2; ++mt) {
        const int lr0 = w * 32 + mt * 16 + q * 4;
        #pragma unroll
        for (int nt = 0; nt < 4; ++nt) {
            const int lc = nt * 16 + m;
            float o[4];
            #pragma unroll
            for (int r = 0; r < 4; ++r) {
                const float d2 = sqA[lr0 + r] + sqB[lc] - 2.0f * acc[mt][nt][r];
                o[r] = (d2 > 0.f) ? sqrtf(d2) : 0.f;
            }
            #pragma unroll
            for (int r = 0; r < 4; ++r)
                distp[(size_t)(row0 + lr0 + r) * NN + col0 + lc] = o[r];
            if (below) {
                const float4 o4 = make_float4(o[0], o[1], o[2], o[3]);
                *reinterpret_cast<float4*>(&distp[(size_t)(col0 + lc) * NN + row0 + lr0]) = o4;
            }
        }
    }
}

// ---------------- kernel 2: row-pair scans + shared window lookup ----------
// first idx in [lo,hi) with key[idx] >= d (right segment: keys non-decreasing)
__device__ __forceinline__ int bs_right(const float* key, float d, int lo, int hi) {
    while (lo < hi) {
        const int mid = (lo + hi) >> 1;
        if (key[mid] >= d) hi = mid; else lo = mid + 1;
    }
    return lo;
}
// first idx in [lo,hi) with key[idx] < d (left segment: keys non-increasing)
__device__ __forceinline__ int bs_left(const float* key, float d, int lo, int hi) {
    while (lo < hi) {
        const int mid = (lo + hi) >> 1;
        if (key[mid] < d) hi = mid; else lo = mid + 1;
    }
    return lo;
}

__global__ __launch_bounds__(256) void row_kernel(const float* __restrict__ distp,
                                                  const float* __restrict__ slab,
                                                  double* __restrict__ rowval,
                                                  int* __restrict__ cnt,
                                                  float* __restrict__ out) {
    __shared__ float key[NN];
    __shared__ float Pf[NN];
    __shared__ float Sf[NN + 1];
    __shared__ float wmxA[4], wmxB[4], wps[4], wss[4];
    __shared__ double wDA[4], wLA[4], wDB[4], wLB[4];
    __shared__ int lastFlag;

    const int pr = blockIdx.x;           // pair index
    const int rA = 2 * pr, rB = 2 * pr + 1;
    const int t = threadIdx.x;
    const int lane = t & 63;
    const int w = t >> 6;
    const float x = slab[rA];
    const float negInvT = -1.0f / 0.07f;
    const float* drowA = &distp[(size_t)rA * NN];
    const float* drowB = &distp[(size_t)rB * NN];

    // ---- keys (shared by both rows), vals for both rows, row maxima ----
    #pragma unroll
    for (int e = 0; e < 2; ++e) {
        const int p4 = t + e * NT;
        const float4 l4 = reinterpret_cast<const float4*>(slab)[p4];
        key[p4 * 4 + 0] = fabsf(l4.x - x);
        key[p4 * 4 + 1] = fabsf(l4.y - x);
        key[p4 * 4 + 2] = fabsf(l4.z - x);
        key[p4 * 4 + 3] = fabsf(l4.w - x);
    }
    const int cb = t * 8;
    float vA[8], vB[8];
    double dsumA = 0.0, dsumB = 0.0;
    float mxA = NEGINF, mxB = NEGINF;
    #pragma unroll
    for (int e = 0; e < 2; ++e) {
        const float4 a4 = reinterpret_cast<const float4*>(drowA)[2 * t + e];
        const float4 b4 = reinterpret_cast<const float4*>(drowB)[2 * t + e];
        const float av[4] = {a4.x, a4.y, a4.z, a4.w};
        const float bv[4] = {b4.x, b4.y, b4.z, b4.w};
        #pragma unroll
        for (int c = 0; c < 4; ++c) {
            const int pc = cb + e * 4 + c;
            if (pc == rA) vA[e * 4 + c] = NEGINF;
            else { const float vv = av[c] * negInvT; vA[e * 4 + c] = vv; mxA = fmaxf(mxA, vv); dsumA += (double)av[c]; }
            if (pc == rB) vB[e * 4 + c] = NEGINF;
            else { const float vv = bv[c] * negInvT; vB[e * 4 + c] = vv; mxB = fmaxf(mxB, vv); dsumB += (double)bv[c]; }
        }
    }
    #pragma unroll
    for (int st = 32; st > 0; st >>= 1) {
        mxA = fmaxf(mxA, __shfl_down(mxA, st));
        mxB = fmaxf(mxB, __shfl_down(mxB, st));
    }
    if (lane == 0) { wmxA[w] = mxA; wmxB[w] = mxB; }
    __syncthreads();   // B1: keys + wave maxima ready
    const float MA = fmaxf(fmaxf(wmxA[0], wmxA[1]), fmaxf(wmxA[2], wmxA[3]));
    const float MB = fmaxf(fmaxf(wmxB[0], wmxB[1]), fmaxf(wmxB[2], wmxB[3]));

    // ---- window boundaries ONCE (key-determined, shared by both rows) ----
    int L8[8], R8[8];
    const int a = cb, b = cb + 7;
    {
        const int le = (rA - 1 < b) ? rA - 1 : b;
        if (a <= le) {
            const float da = key[a];
            const int Ra = bs_right(key, da, rA, NN);
            int Rl = Ra;
            if (le > a) Rl = bs_right(key, key[le], rA, Ra);
            for (int p = a; p <= le; ++p) {
                const float d = key[p];
                int R;
                if (p == a) R = Ra;
                else if (p == le) R = Rl;
                else R = bs_right(key, d, Rl, Ra);
                int L = p + 1;
                while (L < rA && key[L] == d) ++L;
                L8[p - a] = L; R8[p - a] = R;
            }
        }
        const int rs = (rA + 1 > a) ? rA + 1 : a;
        if (rs <= b) {
            const float dr = key[rs];
            const int Lr = bs_left(key, dr, 0, rA);
            int Lb = Lr;
            if (b > rs) Lb = bs_left(key, key[b], 0, Lr);
            for (int p = rs; p <= b; ++p) {
                const float d = key[p];
                int L;
                if (p == rs) L = Lr;
                else if (p == b) L = Lb;
                else L = bs_left(key, d, Lb, Lr);
                int R = p;
                while (R > rA && key[R - 1] == d) --R;
                L8[p - a] = L; R8[p - a] = R;
            }
        }
        if (rA >= a && rA <= b) { L8[rA - a] = rA; R8[rA - a] = rA; }
    }

    // ================= row A: scans + accumulate =================
    double lnsumA = 0.0;
    {
        float e8[8];
        #pragma unroll
        for (int jj = 0; jj < 8; ++jj) e8[jj] = __expf(vA[jj] - MA + CS);
        // fused prefix+suffix wave scans, ONE barrier
        float ex[8], sx[8], xofsP, xofsS;
        {
            float run = 0.f;
            #pragma unroll
            for (int jj = 0; jj < 8; ++jj) { ex[jj] = run; run += e8[jj]; }
            float incP = run;
            #pragma unroll
            for (int st = 1; st < 64; st <<= 1) {
                const float nm = __shfl_up(incP, st);
                if (lane >= st) incP += nm;
            }
            xofsP = __shfl_up(incP, 1);
            if (lane == 0) xofsP = 0.f;
            if (lane == 63) wps[w] = incP;

            float runS = 0.f;
            #pragma unroll
            for (int jj = 7; jj >= 0; --jj) { runS += e8[jj]; sx[jj] = runS; }
            float incS = runS;
            #pragma unroll
            for (int st = 1; st < 64; st <<= 1) {
                const float nm = __shfl_down(incS, st);
                if (lane + st < 64) incS += nm;
            }
            xofsS = __shfl_down(incS, 1);
            if (lane == 63) xofsS = 0.f;
            if (lane == 0) wss[w] = incS;
        }
        __syncthreads();   // B2: wps+wss ready
        #pragma unroll
        for (int ww = 0; ww < 3; ++ww)
            if (ww < w) xofsP += wps[ww];
        #pragma unroll
        for (int ww = 1; ww < 4; ++ww)
            if (ww > w) xofsS += wss[ww];
        #pragma unroll
        for (int jj = 0; jj < 8; ++jj) Pf[cb + jj] = ex[jj] + xofsP;
        #pragma unroll
        for (int jj = 0; jj < 8; ++jj) Sf[cb + jj] = sx[jj] + xofsS;
        if (t == 0) Sf[NN] = 0.f;
        __syncthreads();   // B3: Pf/Sf(A) ready
        const float MBA = MA - CS;
        #pragma unroll
        for (int jj = 0; jj < 8; ++jj) {
            const int p = cb + jj;
            if (p == rA) continue;
            const float s = fmaxf(Pf[L8[jj]] + Sf[R8[jj]], 1e-38f);
            lnsumA += (double)(MBA + __logf(s));
        }
    }
    __syncthreads();   // B4: done reading Pf/Sf(A)

    // ================= row B: scans + accumulate =================
    double lnsumB = 0.0;
    {
        float e8[8];
        #pragma unroll
        for (int jj = 0; jj < 8; ++jj) e8[jj] = __expf(vB[jj] - MB + CS);
        float ex[8], sx[8], xofsP, xofsS;
        {
            float run = 0.f;
            #pragma unroll
            for (int jj = 0; jj < 8; ++jj) { ex[jj] = run; run += e8[jj]; }
            float incP = run;
            #pragma unroll
            for (int st = 1; st < 64; st <<= 1) {
                const float nm = __shfl_up(incP, st);
                if (lane >= st) incP += nm;
            }
            xofsP = __shfl_up(incP, 1);
            if (lane == 0) xofsP = 0.f;
            if (lane == 63) wps[w] = incP;

            float runS = 0.f;
            #pragma unroll
            for (int jj = 7; jj >= 0; --jj) { runS += e8[jj]; sx[jj] = runS; }
            float incS = runS;
            #pragma unroll
            for (int st = 1; st < 64; st <<= 1) {
                const float nm = __shfl_down(incS, st);
                if (lane + st < 64) incS += nm;
            }
            xofsS = __shfl_down(incS, 1);
            if (lane == 63) xofsS = 0.f;
            if (lane == 0) wss[w] = incS;
        }
        __syncthreads();   // B5: wps+wss ready
        #pragma unroll
        for (int ww = 0; ww < 3; ++ww)
            if (ww < w) xofsP += wps[ww];
        #pragma unroll
        for (int ww = 1; ww < 4; ++ww)
            if (ww > w) xofsS += wss[ww];
        #pragma unroll
        for (int jj = 0; jj < 8; ++jj) Pf[cb + jj] = ex[jj] + xofsP;
        #pragma unroll
        for (int jj = 0; jj < 8; ++jj) Sf[cb + jj] = sx[jj] + xofsS;
        if (t == 0) Sf[NN] = 0.f;
        __syncthreads();   // B6: Pf/Sf(B) ready
        const float MBB = MB - CS;
        #pragma unroll
        for (int jj = 0; jj < 8; ++jj) {
            const int p = cb + jj;
            if (p == rB) continue;
            const float s = fmaxf(Pf[L8[jj]] + Sf[R8[jj]], 1e-38f);
            lnsumB += (double)(MBB + __logf(s));
        }
    }

    // ---- reductions (both rows) ----
    #pragma unroll
    for (int st = 32; st > 0; st >>= 1) {
        dsumA  += __shfl_down(dsumA, st);
        lnsumA += __shfl_down(lnsumA, st);
        dsumB  += __shfl_down(dsumB, st);
        lnsumB += __shfl_down(lnsumB, st);
    }
    if (lane == 0) { wDA[w] = dsumA; wLA[w] = lnsumA; wDB[w] = dsumB; wLB[w] = lnsumB; }
    __syncthreads();   // B7
    if (t == 0) {
        const double pairv = ((-(wDA[0] + wDA[1] + wDA[2] + wDA[3]) / 0.07)
                              - (wLA[0] + wLA[1] + wLA[2] + wLA[3]))
                           + ((-(wDB[0] + wDB[1] + wDB[2] + wDB[3]) / 0.07)
                              - (wLB[0] + wLB[1] + wLB[2] + wLB[3]));
        rowval[pr] = pairv;                 // plain store (no CAS)
        __threadfence();                    // visible device-wide before count
        const int old = __hip_atomic_fetch_add(cnt, 1, __ATOMIC_ACQ_REL,
                                               __HIP_MEMORY_SCOPE_AGENT);
        lastFlag = (old == NN / 2 - 1);
    }
    __syncthreads();   // B8: lastFlag ready
    if (lastFlag) {
        // final reduction of 1024 pair partials; key[] is dead -> reuse as f64 buf
        double* red = reinterpret_cast<double*>(key);
        double s = 0.0;
        for (int j = t; j < NN / 2; j += NT)
            s += __hip_atomic_load(&rowval[j], __ATOMIC_RELAXED,
                                   __HIP_MEMORY_SCOPE_AGENT);
        red[t] = s;
        __syncthreads();
        for (int ofs = NT / 2; ofs > 0; ofs >>= 1) {
            if (t < ofs) red[t] += red[t + ofs];
            __syncthreads();
        }
        if (t == 0)
            out[0] = (float)(-red[0] / ((double)NN * (double)(NN - 1)));
    }
}

extern "C" void kernel_launch(void* const* d_in, const int* in_sizes, int n_in,
                              void* d_out, int out_size, void* d_ws, size_t ws_size,
                              hipStream_t stream) {
    const float* features = (const float*)d_in[0];  // [1024, 2, 512] fp32
    const float* labels   = (const float*)d_in[1];  // [1024] fp32
    float* out = (float*)d_out;

    char* ws = (char*)d_ws;
    size_t off = 0;
    float*  sq     = (float*) (ws + off); off += NN * sizeof(float);
    float*  slab   = (float*) (ws + off); off += NN * sizeof(float);
    int*    sj     = (int*)   (ws + off); off += NN * sizeof(int);
    int*    cnt    = (int*)   (ws + off); off += 2 * sizeof(int);
    double* rowval = (double*)(ws + off); off += (NN / 2) * sizeof(double);
    ushort* Ahi    = (ushort*)(ws + off); off += (size_t)NN * DD * sizeof(ushort);
    ushort* Alo    = (ushort*)(ws + off); off += (size_t)NN * DD * sizeof(ushort);
    float*  distp  = (float*) (ws + off); off += (size_t)NN * NN * sizeof(float);

    prep_sort_kernel<<<258, 512, 0, stream>>>(features, labels, Ahi, Alo, sq, slab, sj, cnt);
    gemm_dist_kernel<<<16 * 17, NT, 0, stream>>>(Ahi, Alo, sq, sj, distp);  // 272 lower tiles
    row_kernel<<<NN / 2, NT, 0, stream>>>(distp, slab, rowval, cnt, out);
}

// Round 5
// 143.399 us; speedup vs baseline: 1.1758x; 1.1758x over previous
//
#include <hip/hip_runtime.h>
#include <math.h>

// SupCR loss, MI355X. Round 13 (tail revert):
//  - Rounds 10-12 regression isolated to the device-scope atomic/fence tail in
//    row_kernel (+25-35 us: per-block L2 writeback/invalidate across 8
//    non-coherent XCD L2s). Reverted to round-8 tail: plain rowval stores +
//    separate 1-block finalize kernel. NO fences/atomics anywhere.
//  - Kept (measured neutral/positive): fused prep+rank-sort kernel,
//    round-12 fused-barrier scans (one barrier per scan pair, same math).
//  - GEMM: round-8 exact (128x64 reg-staged, 272 lower-band tiles).
//  Launches: prep_sort, gemm, row, finalize = 4.

#define NN 2048      // N = B*V
#define BB 1024      // B
#define DD 512       // D
#define NT 256
#define NEGINF (-INFINITY)
#define CS 64.0f     // exponent pre-scale bias

typedef short s16x8 __attribute__((ext_vector_type(8)));
typedef float f32x4 __attribute__((ext_vector_type(4)));

// row i of the virtual cf matrix lives at F + ((i%B)*2 + i/B)*D
__device__ __forceinline__ const float* cf_row(const float* F, int i) {
    return F + ((size_t)(i & (BB - 1)) * 2 + (size_t)(i >> 10)) * DD;
}

__device__ __forceinline__ unsigned bf_rne(float x) {
    const unsigned u = __float_as_uint(x);
    return (u + 0x7FFFu + ((u >> 16) & 1u)) >> 16;
}
__device__ __forceinline__ float bf_val(unsigned h) {
    return __uint_as_float(h << 16);
}

// ---------------- kernel 0: fused prep (blocks 0..255) + rank sort (256,257) ----
__global__ __launch_bounds__(512) void prep_sort_kernel(const float* __restrict__ F,
                                                        const float* __restrict__ labels,
                                                        ushort* __restrict__ Ahi,
                                                        ushort* __restrict__ Alo,
                                                        float* __restrict__ sq,
                                                        float* __restrict__ slab,
                                                        int* __restrict__ sj) {
    __shared__ float lab[BB];
    const int blk = blockIdx.x;
    const int t = threadIdx.x;

    if (blk < 256) {
        // ---- prep: 8 rows per block, one row per wave ----
        const int lane = t & 63;
        const int w = t >> 6;
        const int i = blk * 8 + w;
        const float* src = cf_row(F, i);
        const float4 v0 = reinterpret_cast<const float4*>(src)[lane];
        const float4 v1 = reinterpret_cast<const float4*>(src)[lane + 64];
        float ss = v0.x * v0.x + v0.y * v0.y + v0.z * v0.z + v0.w * v0.w
                 + v1.x * v1.x + v1.y * v1.y + v1.z * v1.z + v1.w * v1.w;
        #pragma unroll
        for (int st = 32; st > 0; st >>= 1) ss += __shfl_down(ss, st);
        if (lane == 0) sq[i] = ss;

        const float a[8] = {v0.x, v0.y, v0.z, v0.w, v1.x, v1.y, v1.z, v1.w};
        ushort h[8], l[8];
        #pragma unroll
        for (int e = 0; e < 8; ++e) {
            const unsigned hb = bf_rne(a[e]);
            h[e] = (ushort)hb;
            l[e] = (ushort)bf_rne(a[e] - bf_val(hb));
        }
        const size_t base = (size_t)i * DD;
        *reinterpret_cast<ushort4*>(&Ahi[base + lane * 4])       = make_ushort4(h[0], h[1], h[2], h[3]);
        *reinterpret_cast<ushort4*>(&Ahi[base + 256 + lane * 4]) = make_ushort4(h[4], h[5], h[6], h[7]);
        *reinterpret_cast<ushort4*>(&Alo[base + lane * 4])       = make_ushort4(l[0], l[1], l[2], l[3]);
        *reinterpret_cast<ushort4*>(&Alo[base + 256 + lane * 4]) = make_ushort4(l[4], l[5], l[6], l[7]);
    } else {
        // ---- rank sort: block 256 -> elements 0..511, block 257 -> 512..1023 ----
        lab[t] = labels[t];
        lab[t + 512] = labels[t + 512];
        __syncthreads();
        const int e = (blk - 256) * 512 + t;
        const float li = lab[e];
        int rank = 0;
        const float4* l4 = reinterpret_cast<const float4*>(lab);
        #pragma unroll 4
        for (int j = 0; j < BB / 4; ++j) {
            const float4 v = l4[j];
            const int j0 = j * 4;
            rank += (v.x < li) || (v.x == li && (j0 + 0) < e);
            rank += (v.y < li) || (v.y == li && (j0 + 1) < e);
            rank += (v.z < li) || (v.z == li && (j0 + 2) < e);
            rank += (v.w < li) || (v.w == li && (j0 + 3) < e);
        }
        slab[2 * rank]     = li;
        slab[2 * rank + 1] = li;
        sj[2 * rank]     = e;
        sj[2 * rank + 1] = e + BB;
    }
}

// ---------------- kernel 1: MFMA dist, symmetric (lower tiles only) ---------
#define TM 128
#define TN 64
#define TK 32
__global__ __launch_bounds__(256) void gemm_dist_kernel(const ushort* __restrict__ Ahi,
                                                        const ushort* __restrict__ Alo,
                                                        const float* __restrict__ sq,
                                                        const int* __restrict__ sj,
                                                        float* __restrict__ distp) {
    __shared__ ushort Ah[4][TM][8];
    __shared__ ushort Al[4][TM][8];
    __shared__ ushort Bh[4][TN][8];
    __shared__ ushort Bl[4][TN][8];
    __shared__ int   sjcA[TM];
    __shared__ int   sjcB[TN];
    __shared__ float sqA[TM];
    __shared__ float sqB[TN];

    const int t = threadIdx.x;
    const int lane = t & 63;
    const int w = t >> 6;

    // tile id -> (by, bx) over the lower-triangular band: C(by)=by*(by+1)
    const int id = blockIdx.x;
    int by = (int)((__fsqrt_rn(4.0f * (float)id + 1.0f) - 1.0f) * 0.5f);
    while ((by + 1) * (by + 2) <= id) ++by;
    while (by * (by + 1) > id) --by;
    const int bx = id - by * (by + 1);          // 0 .. 2*by+1
    const int row0 = by * TM;
    const int col0 = bx * TN;
    const bool below = (bx < 2 * by);           // strictly left of diag square

    if (t < TM) {
        const int s = sj[row0 + t];
        sjcA[t] = s; sqA[t] = sq[s];
    } else if (t < TM + TN) {
        const int u = t - TM;
        const int s = sj[col0 + u];
        sjcB[u] = s; sqB[u] = sq[s];
    }
    __syncthreads();
    const int rr = t >> 2;
    const int cq = t & 3;
    const size_t gA0 = (size_t)sjcA[rr] * DD + cq * 8;
    const size_t gA1 = (size_t)sjcA[64 + rr] * DD + cq * 8;
    const size_t gB0 = (size_t)sjcB[rr] * DD + cq * 8;

    f32x4 acc[2][4] = {};
    const int m = lane & 15;
    const int q = lane >> 4;

    for (int kt = 0; kt < DD / TK; ++kt) {
        __syncthreads();
        const size_t ko = (size_t)kt * TK;
        *reinterpret_cast<int4*>(&Ah[cq][rr][0])      = *reinterpret_cast<const int4*>(&Ahi[gA0 + ko]);
        *reinterpret_cast<int4*>(&Al[cq][rr][0])      = *reinterpret_cast<const int4*>(&Alo[gA0 + ko]);
        *reinterpret_cast<int4*>(&Ah[cq][64 + rr][0]) = *reinterpret_cast<const int4*>(&Ahi[gA1 + ko]);
        *reinterpret_cast<int4*>(&Al[cq][64 + rr][0]) = *reinterpret_cast<const int4*>(&Alo[gA1 + ko]);
        *reinterpret_cast<int4*>(&Bh[cq][rr][0])      = *reinterpret_cast<const int4*>(&Ahi[gB0 + ko]);
        *reinterpret_cast<int4*>(&Bl[cq][rr][0])      = *reinterpret_cast<const int4*>(&Alo[gB0 + ko]);
        __syncthreads();

        s16x8 fah[2], fal[2], fbh[4], fbl[4];
        #pragma unroll
        for (int mt = 0; mt < 2; ++mt) {
            fah[mt] = *reinterpret_cast<const s16x8*>(&Ah[q][w * 32 + mt * 16 + m][0]);
            fal[mt] = *reinterpret_cast<const s16x8*>(&Al[q][w * 32 + mt * 16 + m][0]);
        }
        #pragma unroll
        for (int nt = 0; nt < 4; ++nt) {
            fbh[nt] = *reinterpret_cast<const s16x8*>(&Bh[q][nt * 16 + m][0]);
            fbl[nt] = *reinterpret_cast<const s16x8*>(&Bl[q][nt * 16 + m][0]);
        }
        #pragma unroll
        for (int mt = 0; mt < 2; ++mt)
            #pragma unroll
            for (int nt = 0; nt < 4; ++nt) {
                acc[mt][nt] = __builtin_amdgcn_mfma_f32_16x16x32_bf16(fah[mt], fbh[nt], acc[mt][nt], 0, 0, 0);
                acc[mt][nt] = __builtin_amdgcn_mfma_f32_16x16x32_bf16(fah[mt], fbl[nt], acc[mt][nt], 0, 0, 0);
                acc[mt][nt] = __builtin_amdgcn_mfma_f32_16x16x32_bf16(fal[mt], fbh[nt], acc[mt][nt], 0, 0, 0);
            }
    }

    #pragma unroll
    for (int mt = 0; mt < 2; ++mt) {
        const int lr0 = w * 32 + mt * 16 + q * 4;
        #pragma unroll
        for (int nt = 0; nt < 4; ++nt) {
            const int lc = nt * 16 + m;
            float o[4];
            #pragma unroll
            for (int r = 0; r < 4; ++r) {
                const float d2 = sqA[lr0 + r] + sqB[lc] - 2.0f * acc[mt][nt][r];
                o[r] = (d2 > 0.f) ? sqrtf(d2) : 0.f;
            }
            #pragma unroll
            for (int r = 0; r < 4; ++r)
                distp[(size_t)(row0 + lr0 + r) * NN + col0 + lc] = o[r];
            if (below) {
                const float4 o4 = make_float4(o[0], o[1], o[2], o[3]);
                *reinterpret_cast<float4*>(&distp[(size_t)(col0 + lc) * NN + row0 + lr0]) = o4;
            }
        }
    }
}

// ---------------- kernel 2: row-pair scans + shared window lookup ----------
// first idx in [lo,hi) with key[idx] >= d (right segment: keys non-decreasing)
__device__ __forceinline__ int bs_right(const float* key, float d, int lo, int hi) {
    while (lo < hi) {
        const int mid = (lo + hi) >> 1;
        if (key[mid] >= d) hi = mid; else lo = mid + 1;
    }
    return lo;
}
// first idx in [lo,hi) with key[idx] < d (left segment: keys non-increasing)
__device__ __forceinline__ int bs_left(const float* key, float d, int lo, int hi) {
    while (lo < hi) {
        const int mid = (lo + hi) >> 1;
        if (key[mid] < d) hi = mid; else lo = mid + 1;
    }
    return lo;
}

__global__ __launch_bounds__(256) void row_kernel(const float* __restrict__ distp,
                                                  const float* __restrict__ slab,
                                                  double* __restrict__ rowval) {
    __shared__ float key[NN];
    __shared__ float Pf[NN];
    __shared__ float Sf[NN + 1];
    __shared__ float wmxA[4], wmxB[4], wps[4], wss[4];
    __shared__ double wDA[4], wLA[4], wDB[4], wLB[4];

    const int pr = blockIdx.x;           // pair index
    const int rA = 2 * pr, rB = 2 * pr + 1;
    const int t = threadIdx.x;
    const int lane = t & 63;
    const int w = t >> 6;
    const float x = slab[rA];
    const float negInvT = -1.0f / 0.07f;
    const float* drowA = &distp[(size_t)rA * NN];
    const float* drowB = &distp[(size_t)rB * NN];

    // ---- keys (shared by both rows), vals for both rows, row maxima ----
    #pragma unroll
    for (int e = 0; e < 2; ++e) {
        const int p4 = t + e * NT;
        const float4 l4 = reinterpret_cast<const float4*>(slab)[p4];
        key[p4 * 4 + 0] = fabsf(l4.x - x);
        key[p4 * 4 + 1] = fabsf(l4.y - x);
        key[p4 * 4 + 2] = fabsf(l4.z - x);
        key[p4 * 4 + 3] = fabsf(l4.w - x);
    }
    const int cb = t * 8;
    float vA[8], vB[8];
    double dsumA = 0.0, dsumB = 0.0;
    float mxA = NEGINF, mxB = NEGINF;
    #pragma unroll
    for (int e = 0; e < 2; ++e) {
        const float4 a4 = reinterpret_cast<const float4*>(drowA)[2 * t + e];
        const float4 b4 = reinterpret_cast<const float4*>(drowB)[2 * t + e];
        const float av[4] = {a4.x, a4.y, a4.z, a4.w};
        const float bv[4] = {b4.x, b4.y, b4.z, b4.w};
        #pragma unroll
        for (int c = 0; c < 4; ++c) {
            const int pc = cb + e * 4 + c;
            if (pc == rA) vA[e * 4 + c] = NEGINF;
            else { const float vv = av[c] * negInvT; vA[e * 4 + c] = vv; mxA = fmaxf(mxA, vv); dsumA += (double)av[c]; }
            if (pc == rB) vB[e * 4 + c] = NEGINF;
            else { const float vv = bv[c] * negInvT; vB[e * 4 + c] = vv; mxB = fmaxf(mxB, vv); dsumB += (double)bv[c]; }
        }
    }
    #pragma unroll
    for (int st = 32; st > 0; st >>= 1) {
        mxA = fmaxf(mxA, __shfl_down(mxA, st));
        mxB = fmaxf(mxB, __shfl_down(mxB, st));
    }
    if (lane == 0) { wmxA[w] = mxA; wmxB[w] = mxB; }
    __syncthreads();   // B1: keys + wave maxima ready
    const float MA = fmaxf(fmaxf(wmxA[0], wmxA[1]), fmaxf(wmxA[2], wmxA[3]));
    const float MB = fmaxf(fmaxf(wmxB[0], wmxB[1]), fmaxf(wmxB[2], wmxB[3]));

    // ---- window boundaries ONCE (key-determined, shared by both rows) ----
    int L8[8], R8[8];
    const int a = cb, b = cb + 7;
    {
        const int le = (rA - 1 < b) ? rA - 1 : b;
        if (a <= le) {
            const float da = key[a];
            const int Ra = bs_right(key, da, rA, NN);
            int Rl = Ra;
            if (le > a) Rl = bs_right(key, key[le], rA, Ra);
            for (int p = a; p <= le; ++p) {
                const float d = key[p];
                int R;
                if (p == a) R = Ra;
                else if (p == le) R = Rl;
                else R = bs_right(key, d, Rl, Ra);
                int L = p + 1;
                while (L < rA && key[L] == d) ++L;
                L8[p - a] = L; R8[p - a] = R;
            }
        }
        const int rs = (rA + 1 > a) ? rA + 1 : a;
        if (rs <= b) {
            const float dr = key[rs];
            const int Lr = bs_left(key, dr, 0, rA);
            int Lb = Lr;
            if (b > rs) Lb = bs_left(key, key[b], 0, Lr);
            for (int p = rs; p <= b; ++p) {
                const float d = key[p];
                int L;
                if (p == rs) L = Lr;
                else if (p == b) L = Lb;
                else L = bs_left(key, d, Lb, Lr);
                int R = p;
                while (R > rA && key[R - 1] == d) --R;
                L8[p - a] = L; R8[p - a] = R;
            }
        }
        if (rA >= a && rA <= b) { L8[rA - a] = rA; R8[rA - a] = rA; }
    }

    // ================= row A: scans + accumulate =================
    double lnsumA = 0.0;
    {
        float e8[8];
        #pragma unroll
        for (int jj = 0; jj < 8; ++jj) e8[jj] = __expf(vA[jj] - MA + CS);
        // fused prefix+suffix wave scans, ONE barrier
        float ex[8], sx[8], xofsP, xofsS;
        {
            float run = 0.f;
            #pragma unroll
            for (int jj = 0; jj < 8; ++jj) { ex[jj] = run; run += e8[jj]; }
            float incP = run;
            #pragma unroll
            for (int st = 1; st < 64; st <<= 1) {
                const float nm = __shfl_up(incP, st);
                if (lane >= st) incP += nm;
            }
            xofsP = __shfl_up(incP, 1);
            if (lane == 0) xofsP = 0.f;
            if (lane == 63) wps[w] = incP;

            float runS = 0.f;
            #pragma unroll
            for (int jj = 7; jj >= 0; --jj) { runS += e8[jj]; sx[jj] = runS; }
            float incS = runS;
            #pragma unroll
            for (int st = 1; st < 64; st <<= 1) {
                const float nm = __shfl_down(incS, st);
                if (lane + st < 64) incS += nm;
            }
            xofsS = __shfl_down(incS, 1);
            if (lane == 63) xofsS = 0.f;
            if (lane == 0) wss[w] = incS;
        }
        __syncthreads();   // B2: wps+wss ready
        #pragma unroll
        for (int ww = 0; ww < 3; ++ww)
            if (ww < w) xofsP += wps[ww];
        #pragma unroll
        for (int ww = 1; ww < 4; ++ww)
            if (ww > w) xofsS += wss[ww];
        #pragma unroll
        for (int jj = 0; jj < 8; ++jj) Pf[cb + jj] = ex[jj] + xofsP;
        #pragma unroll
        for (int jj = 0; jj < 8; ++jj) Sf[cb + jj] = sx[jj] + xofsS;
        if (t == 0) Sf[NN] = 0.f;
        __syncthreads();   // B3: Pf/Sf(A) ready
        const float MBA = MA - CS;
        #pragma unroll
        for (int jj = 0; jj < 8; ++jj) {
            const int p = cb + jj;
            if (p == rA) continue;
            const float s = fmaxf(Pf[L8[jj]] + Sf[R8[jj]], 1e-38f);
            lnsumA += (double)(MBA + __logf(s));
        }
    }
    __syncthreads();   // B4: done reading Pf/Sf(A)

    // ================= row B: scans + accumulate =================
    double lnsumB = 0.0;
    {
        float e8[8];
        #pragma unroll
        for (int jj = 0; jj < 8; ++jj) e8[jj] = __expf(vB[jj] - MB + CS);
        float ex[8], sx[8], xofsP, xofsS;
        {
            float run = 0.f;
            #pragma unroll
            for (int jj = 0; jj < 8; ++jj) { ex[jj] = run; run += e8[jj]; }
            float incP = run;
            #pragma unroll
            for (int st = 1; st < 64; st <<= 1) {
                const float nm = __shfl_up(incP, st);
                if (lane >= st) incP += nm;
            }
            xofsP = __shfl_up(incP, 1);
            if (lane == 0) xofsP = 0.f;
            if (lane == 63) wps[w] = incP;

            float runS = 0.f;
            #pragma unroll
            for (int jj = 7; jj >= 0; --jj) { runS += e8[jj]; sx[jj] = runS; }
            float incS = runS;
            #pragma unroll
            for (int st = 1; st < 64; st <<= 1) {
                const float nm = __shfl_down(incS, st);
                if (lane + st < 64) incS += nm;
            }
            xofsS = __shfl_down(incS, 1);
            if (lane == 63) xofsS = 0.f;
            if (lane == 0) wss[w] = incS;
        }
        __syncthreads();   // B5: wps+wss ready
        #pragma unroll
        for (int ww = 0; ww < 3; ++ww)
            if (ww < w) xofsP += wps[ww];
        #pragma unroll
        for (int ww = 1; ww < 4; ++ww)
            if (ww > w) xofsS += wss[ww];
        #pragma unroll
        for (int jj = 0; jj < 8; ++jj) Pf[cb + jj] = ex[jj] + xofsP;
        #pragma unroll
        for (int jj = 0; jj < 8; ++jj) Sf[cb + jj] = sx[jj] + xofsS;
        if (t == 0) Sf[NN] = 0.f;
        __syncthreads();   // B6: Pf/Sf(B) ready
        const float MBB = MB - CS;
        #pragma unroll
        for (int jj = 0; jj < 8; ++jj) {
            const int p = cb + jj;
            if (p == rB) continue;
            const float s = fmaxf(Pf[L8[jj]] + Sf[R8[jj]], 1e-38f);
            lnsumB += (double)(MBB + __logf(s));
        }
    }

    // ---- reductions (both rows) ----
    #pragma unroll
    for (int st = 32; st > 0; st >>= 1) {
        dsumA  += __shfl_down(dsumA, st);
        lnsumA += __shfl_down(lnsumA, st);
        dsumB  += __shfl_down(dsumB, st);
        lnsumB += __shfl_down(lnsumB, st);
    }
    if (lane == 0) { wDA[w] = dsumA; wLA[w] = lnsumA; wDB[w] = dsumB; wLB[w] = lnsumB; }
    __syncthreads();   // B7
    if (t == 0) {
        rowval[rA] = (-(wDA[0] + wDA[1] + wDA[2] + wDA[3]) / 0.07)
                   - (wLA[0] + wLA[1] + wLA[2] + wLA[3]);
        rowval[rB] = (-(wDB[0] + wDB[1] + wDB[2] + wDB[3]) / 0.07)
                   - (wLB[0] + wLB[1] + wLB[2] + wLB[3]);
    }
}

// ---------------- kernel 3: final mean ----------------
__global__ __launch_bounds__(256) void finalize_kernel(const double* __restrict__ rowval,
                                                       float* __restrict__ out) {
    __shared__ double red[NT];
    const int t = threadIdx.x;
    double s = 0.0;
    for (int j = t; j < NN; j += NT) s += rowval[j];
    red[t] = s;
    __syncthreads();
    for (int ofs = NT / 2; ofs > 0; ofs >>= 1) {
        if (t < ofs) red[t] += red[t + ofs];
        __syncthreads();
    }
    if (t == 0) {
        out[0] = (float)(-red[0] / ((double)NN * (double)(NN - 1)));
    }
}

extern "C" void kernel_launch(void* const* d_in, const int* in_sizes, int n_in,
                              void* d_out, int out_size, void* d_ws, size_t ws_size,
                              hipStream_t stream) {
    const float* features = (const float*)d_in[0];  // [1024, 2, 512] fp32
    const float* labels   = (const float*)d_in[1];  // [1024] fp32
    float* out = (float*)d_out;

    char* ws = (char*)d_ws;
    size_t off = 0;
    float*  sq     = (float*) (ws + off); off += NN * sizeof(float);
    float*  slab   = (float*) (ws + off); off += NN * sizeof(float);
    int*    sj     = (int*)   (ws + off); off += NN * sizeof(int);
    double* rowval = (double*)(ws + off); off += NN * sizeof(double);
    ushort* Ahi    = (ushort*)(ws + off); off += (size_t)NN * DD * sizeof(ushort);
    ushort* Alo    = (ushort*)(ws + off); off += (size_t)NN * DD * sizeof(ushort);
    float*  distp  = (float*) (ws + off); off += (size_t)NN * NN * sizeof(float);

    prep_sort_kernel<<<258, 512, 0, stream>>>(features, labels, Ahi, Alo, sq, slab, sj);
    gemm_dist_kernel<<<16 * 17, NT, 0, stream>>>(Ahi, Alo, sq, sj, distp);  // 272 lower tiles
    row_kernel<<<NN / 2, NT, 0, stream>>>(distp, slab, rowval);
    finalize_kernel<<<1, NT, 0, stream>>>(rowval, out);
}

// Round 6
// 142.406 us; speedup vs baseline: 1.1840x; 1.0070x over previous
//
#include <hip/hip_runtime.h>
#include <math.h>

// SupCR loss, MI355X. Round 14 (A/B isolate):
//  = Round 8 config exactly (fastest measured: 133.1 us), minus one launch:
//  - prep_sort: fused bf16 split/norms + parallel rank sort (neutral, r9/r13).
//  - GEMM: r8 exact (128x64 reg-staged, 272 lower-band tiles).
//  - row_kernel: r8 EXACT body -- UNFUSED scans (prefix->B->write, suffix->B->
//    write). The r12/r13 fused-barrier scan (24 extra floats live across a
//    barrier at 40 VGPR) is the only unmeasured delta vs r8's 133.1 and is
//    suspected for r13's +10 us.
//  - Tail: plain rowval stores + 1-block finalize. NO atomics/fences.

#define NN 2048      // N = B*V
#define BB 1024      // B
#define DD 512       // D
#define NT 256
#define NEGINF (-INFINITY)
#define CS 64.0f     // exponent pre-scale bias

typedef short s16x8 __attribute__((ext_vector_type(8)));
typedef float f32x4 __attribute__((ext_vector_type(4)));

// row i of the virtual cf matrix lives at F + ((i%B)*2 + i/B)*D
__device__ __forceinline__ const float* cf_row(const float* F, int i) {
    return F + ((size_t)(i & (BB - 1)) * 2 + (size_t)(i >> 10)) * DD;
}

__device__ __forceinline__ unsigned bf_rne(float x) {
    const unsigned u = __float_as_uint(x);
    return (u + 0x7FFFu + ((u >> 16) & 1u)) >> 16;
}
__device__ __forceinline__ float bf_val(unsigned h) {
    return __uint_as_float(h << 16);
}

// ---------------- kernel 0: fused prep (blocks 0..255) + rank sort (256,257) ----
__global__ __launch_bounds__(512) void prep_sort_kernel(const float* __restrict__ F,
                                                        const float* __restrict__ labels,
                                                        ushort* __restrict__ Ahi,
                                                        ushort* __restrict__ Alo,
                                                        float* __restrict__ sq,
                                                        float* __restrict__ slab,
                                                        int* __restrict__ sj) {
    __shared__ float lab[BB];
    const int blk = blockIdx.x;
    const int t = threadIdx.x;

    if (blk < 256) {
        // ---- prep: 8 rows per block, one row per wave ----
        const int lane = t & 63;
        const int w = t >> 6;
        const int i = blk * 8 + w;
        const float* src = cf_row(F, i);
        const float4 v0 = reinterpret_cast<const float4*>(src)[lane];
        const float4 v1 = reinterpret_cast<const float4*>(src)[lane + 64];
        float ss = v0.x * v0.x + v0.y * v0.y + v0.z * v0.z + v0.w * v0.w
                 + v1.x * v1.x + v1.y * v1.y + v1.z * v1.z + v1.w * v1.w;
        #pragma unroll
        for (int st = 32; st > 0; st >>= 1) ss += __shfl_down(ss, st);
        if (lane == 0) sq[i] = ss;

        const float a[8] = {v0.x, v0.y, v0.z, v0.w, v1.x, v1.y, v1.z, v1.w};
        ushort h[8], l[8];
        #pragma unroll
        for (int e = 0; e < 8; ++e) {
            const unsigned hb = bf_rne(a[e]);
            h[e] = (ushort)hb;
            l[e] = (ushort)bf_rne(a[e] - bf_val(hb));
        }
        const size_t base = (size_t)i * DD;
        *reinterpret_cast<ushort4*>(&Ahi[base + lane * 4])       = make_ushort4(h[0], h[1], h[2], h[3]);
        *reinterpret_cast<ushort4*>(&Ahi[base + 256 + lane * 4]) = make_ushort4(h[4], h[5], h[6], h[7]);
        *reinterpret_cast<ushort4*>(&Alo[base + lane * 4])       = make_ushort4(l[0], l[1], l[2], l[3]);
        *reinterpret_cast<ushort4*>(&Alo[base + 256 + lane * 4]) = make_ushort4(l[4], l[5], l[6], l[7]);
    } else {
        // ---- rank sort: block 256 -> elements 0..511, block 257 -> 512..1023 ----
        lab[t] = labels[t];
        lab[t + 512] = labels[t + 512];
        __syncthreads();
        const int e = (blk - 256) * 512 + t;
        const float li = lab[e];
        int rank = 0;
        const float4* l4 = reinterpret_cast<const float4*>(lab);
        #pragma unroll 4
        for (int j = 0; j < BB / 4; ++j) {
            const float4 v = l4[j];
            const int j0 = j * 4;
            rank += (v.x < li) || (v.x == li && (j0 + 0) < e);
            rank += (v.y < li) || (v.y == li && (j0 + 1) < e);
            rank += (v.z < li) || (v.z == li && (j0 + 2) < e);
            rank += (v.w < li) || (v.w == li && (j0 + 3) < e);
        }
        slab[2 * rank]     = li;
        slab[2 * rank + 1] = li;
        sj[2 * rank]     = e;
        sj[2 * rank + 1] = e + BB;
    }
}

// ---------------- kernel 1: MFMA dist, symmetric (lower tiles only) ---------
#define TM 128
#define TN 64
#define TK 32
__global__ __launch_bounds__(256) void gemm_dist_kernel(const ushort* __restrict__ Ahi,
                                                        const ushort* __restrict__ Alo,
                                                        const float* __restrict__ sq,
                                                        const int* __restrict__ sj,
                                                        float* __restrict__ distp) {
    __shared__ ushort Ah[4][TM][8];
    __shared__ ushort Al[4][TM][8];
    __shared__ ushort Bh[4][TN][8];
    __shared__ ushort Bl[4][TN][8];
    __shared__ int   sjcA[TM];
    __shared__ int   sjcB[TN];
    __shared__ float sqA[TM];
    __shared__ float sqB[TN];

    const int t = threadIdx.x;
    const int lane = t & 63;
    const int w = t >> 6;

    // tile id -> (by, bx) over the lower-triangular band: C(by)=by*(by+1)
    const int id = blockIdx.x;
    int by = (int)((__fsqrt_rn(4.0f * (float)id + 1.0f) - 1.0f) * 0.5f);
    while ((by + 1) * (by + 2) <= id) ++by;
    while (by * (by + 1) > id) --by;
    const int bx = id - by * (by + 1);          // 0 .. 2*by+1
    const int row0 = by * TM;
    const int col0 = bx * TN;
    const bool below = (bx < 2 * by);           // strictly left of diag square

    if (t < TM) {
        const int s = sj[row0 + t];
        sjcA[t] = s; sqA[t] = sq[s];
    } else if (t < TM + TN) {
        const int u = t - TM;
        const int s = sj[col0 + u];
        sjcB[u] = s; sqB[u] = sq[s];
    }
    __syncthreads();
    const int rr = t >> 2;
    const int cq = t & 3;
    const size_t gA0 = (size_t)sjcA[rr] * DD + cq * 8;
    const size_t gA1 = (size_t)sjcA[64 + rr] * DD + cq * 8;
    const size_t gB0 = (size_t)sjcB[rr] * DD + cq * 8;

    f32x4 acc[2][4] = {};
    const int m = lane & 15;
    const int q = lane >> 4;

    for (int kt = 0; kt < DD / TK; ++kt) {
        __syncthreads();
        const size_t ko = (size_t)kt * TK;
        *reinterpret_cast<int4*>(&Ah[cq][rr][0])      = *reinterpret_cast<const int4*>(&Ahi[gA0 + ko]);
        *reinterpret_cast<int4*>(&Al[cq][rr][0])      = *reinterpret_cast<const int4*>(&Alo[gA0 + ko]);
        *reinterpret_cast<int4*>(&Ah[cq][64 + rr][0]) = *reinterpret_cast<const int4*>(&Ahi[gA1 + ko]);
        *reinterpret_cast<int4*>(&Al[cq][64 + rr][0]) = *reinterpret_cast<const int4*>(&Alo[gA1 + ko]);
        *reinterpret_cast<int4*>(&Bh[cq][rr][0])      = *reinterpret_cast<const int4*>(&Ahi[gB0 + ko]);
        *reinterpret_cast<int4*>(&Bl[cq][rr][0])      = *reinterpret_cast<const int4*>(&Alo[gB0 + ko]);
        __syncthreads();

        s16x8 fah[2], fal[2], fbh[4], fbl[4];
        #pragma unroll
        for (int mt = 0; mt < 2; ++mt) {
            fah[mt] = *reinterpret_cast<const s16x8*>(&Ah[q][w * 32 + mt * 16 + m][0]);
            fal[mt] = *reinterpret_cast<const s16x8*>(&Al[q][w * 32 + mt * 16 + m][0]);
        }
        #pragma unroll
        for (int nt = 0; nt < 4; ++nt) {
            fbh[nt] = *reinterpret_cast<const s16x8*>(&Bh[q][nt * 16 + m][0]);
            fbl[nt] = *reinterpret_cast<const s16x8*>(&Bl[q][nt * 16 + m][0]);
        }
        #pragma unroll
        for (int mt = 0; mt < 2; ++mt)
            #pragma unroll
            for (int nt = 0; nt < 4; ++nt) {
                acc[mt][nt] = __builtin_amdgcn_mfma_f32_16x16x32_bf16(fah[mt], fbh[nt], acc[mt][nt], 0, 0, 0);
                acc[mt][nt] = __builtin_amdgcn_mfma_f32_16x16x32_bf16(fah[mt], fbl[nt], acc[mt][nt], 0, 0, 0);
                acc[mt][nt] = __builtin_amdgcn_mfma_f32_16x16x32_bf16(fal[mt], fbh[nt], acc[mt][nt], 0, 0, 0);
            }
    }

    #pragma unroll
    for (int mt = 0; mt < 2; ++mt) {
        const int lr0 = w * 32 + mt * 16 + q * 4;
        #pragma unroll
        for (int nt = 0; nt < 4; ++nt) {
            const int lc = nt * 16 + m;
            float o[4];
            #pragma unroll
            for (int r = 0; r < 4; ++r) {
                const float d2 = sqA[lr0 + r] + sqB[lc] - 2.0f * acc[mt][nt][r];
                o[r] = (d2 > 0.f) ? sqrtf(d2) : 0.f;
            }
            #pragma unroll
            for (int r = 0; r < 4; ++r)
                distp[(size_t)(row0 + lr0 + r) * NN + col0 + lc] = o[r];
            if (below) {
                const float4 o4 = make_float4(o[0], o[1], o[2], o[3]);
                *reinterpret_cast<float4*>(&distp[(size_t)(col0 + lc) * NN + row0 + lr0]) = o4;
            }
        }
    }
}

// ---------------- kernel 2: row-pair scans + shared window lookup ----------
// first idx in [lo,hi) with key[idx] >= d (right segment: keys non-decreasing)
__device__ __forceinline__ int bs_right(const float* key, float d, int lo, int hi) {
    while (lo < hi) {
        const int mid = (lo + hi) >> 1;
        if (key[mid] >= d) hi = mid; else lo = mid + 1;
    }
    return lo;
}
// first idx in [lo,hi) with key[idx] < d (left segment: keys non-increasing)
__device__ __forceinline__ int bs_left(const float* key, float d, int lo, int hi) {
    while (lo < hi) {
        const int mid = (lo + hi) >> 1;
        if (key[mid] < d) hi = mid; else lo = mid + 1;
    }
    return lo;
}

__global__ __launch_bounds__(256) void row_kernel(const float* __restrict__ distp,
                                                  const float* __restrict__ slab,
                                                  double* __restrict__ rowval) {
    __shared__ float key[NN];
    __shared__ float Pf[NN];
    __shared__ float Sf[NN + 1];
    __shared__ float wmxA[4], wmxB[4], wps[4], wss[4];
    __shared__ double wDA[4], wLA[4], wDB[4], wLB[4];

    const int pr = blockIdx.x;           // pair index
    const int rA = 2 * pr, rB = 2 * pr + 1;
    const int t = threadIdx.x;
    const int lane = t & 63;
    const int w = t >> 6;
    const float x = slab[rA];
    const float negInvT = -1.0f / 0.07f;
    const float* drowA = &distp[(size_t)rA * NN];
    const float* drowB = &distp[(size_t)rB * NN];

    // ---- keys (shared by both rows), vals for both rows, row maxima ----
    #pragma unroll
    for (int e = 0; e < 2; ++e) {
        const int p4 = t + e * NT;
        const float4 l4 = reinterpret_cast<const float4*>(slab)[p4];
        key[p4 * 4 + 0] = fabsf(l4.x - x);
        key[p4 * 4 + 1] = fabsf(l4.y - x);
        key[p4 * 4 + 2] = fabsf(l4.z - x);
        key[p4 * 4 + 3] = fabsf(l4.w - x);
    }
    const int cb = t * 8;
    float vA[8], vB[8];
    double dsumA = 0.0, dsumB = 0.0;
    float mxA = NEGINF, mxB = NEGINF;
    #pragma unroll
    for (int e = 0; e < 2; ++e) {
        const float4 a4 = reinterpret_cast<const float4*>(drowA)[2 * t + e];
        const float4 b4 = reinterpret_cast<const float4*>(drowB)[2 * t + e];
        const float av[4] = {a4.x, a4.y, a4.z, a4.w};
        const float bv[4] = {b4.x, b4.y, b4.z, b4.w};
        #pragma unroll
        for (int c = 0; c < 4; ++c) {
            const int pc = cb + e * 4 + c;
            if (pc == rA) vA[e * 4 + c] = NEGINF;
            else { const float vv = av[c] * negInvT; vA[e * 4 + c] = vv; mxA = fmaxf(mxA, vv); dsumA += (double)av[c]; }
            if (pc == rB) vB[e * 4 + c] = NEGINF;
            else { const float vv = bv[c] * negInvT; vB[e * 4 + c] = vv; mxB = fmaxf(mxB, vv); dsumB += (double)bv[c]; }
        }
    }
    #pragma unroll
    for (int st = 32; st > 0; st >>= 1) {
        mxA = fmaxf(mxA, __shfl_down(mxA, st));
        mxB = fmaxf(mxB, __shfl_down(mxB, st));
    }
    if (lane == 0) { wmxA[w] = mxA; wmxB[w] = mxB; }
    __syncthreads();   // B1: keys + wave maxima ready
    const float MA = fmaxf(fmaxf(wmxA[0], wmxA[1]), fmaxf(wmxA[2], wmxA[3]));
    const float MB = fmaxf(fmaxf(wmxB[0], wmxB[1]), fmaxf(wmxB[2], wmxB[3]));

    // ---- window boundaries ONCE (key-determined, shared by both rows) ----
    int L8[8], R8[8];
    const int a = cb, b = cb + 7;
    {
        const int le = (rA - 1 < b) ? rA - 1 : b;
        if (a <= le) {
            const float da = key[a];
            const int Ra = bs_right(key, da, rA, NN);
            int Rl = Ra;
            if (le > a) Rl = bs_right(key, key[le], rA, Ra);
            for (int p = a; p <= le; ++p) {
                const float d = key[p];
                int R;
                if (p == a) R = Ra;
                else if (p == le) R = Rl;
                else R = bs_right(key, d, Rl, Ra);
                int L = p + 1;
                while (L < rA && key[L] == d) ++L;
                L8[p - a] = L; R8[p - a] = R;
            }
        }
        const int rs = (rA + 1 > a) ? rA + 1 : a;
        if (rs <= b) {
            const float dr = key[rs];
            const int Lr = bs_left(key, dr, 0, rA);
            int Lb = Lr;
            if (b > rs) Lb = bs_left(key, key[b], 0, Lr);
            for (int p = rs; p <= b; ++p) {
                const float d = key[p];
                int L;
                if (p == rs) L = Lr;
                else if (p == b) L = Lb;
                else L = bs_left(key, d, Lb, Lr);
                int R = p;
                while (R > rA && key[R - 1] == d) --R;
                L8[p - a] = L; R8[p - a] = R;
            }
        }
        if (rA >= a && rA <= b) { L8[rA - a] = rA; R8[rA - a] = rA; }
    }

    // ================= row A: scans + accumulate =================
    double lnsumA = 0.0;
    {
        float e8[8];
        #pragma unroll
        for (int jj = 0; jj < 8; ++jj) e8[jj] = __expf(vA[jj] - MA + CS);
        // prefix
        {
            float run = 0.f, ex[8];
            #pragma unroll
            for (int jj = 0; jj < 8; ++jj) { ex[jj] = run; run += e8[jj]; }
            float inc = run;
            #pragma unroll
            for (int st = 1; st < 64; st <<= 1) {
                const float nm = __shfl_up(inc, st);
                if (lane >= st) inc += nm;
            }
            float xofs = __shfl_up(inc, 1);
            if (lane == 0) xofs = 0.f;
            if (lane == 63) wps[w] = inc;
            __syncthreads();   // B2
            #pragma unroll
            for (int ww = 0; ww < 3; ++ww)
                if (ww < w) xofs += wps[ww];
            #pragma unroll
            for (int jj = 0; jj < 8; ++jj) Pf[cb + jj] = ex[jj] + xofs;
        }
        // suffix
        {
            float run = 0.f, sx[8];
            #pragma unroll
            for (int jj = 7; jj >= 0; --jj) { run += e8[jj]; sx[jj] = run; }
            float inc = run;
            #pragma unroll
            for (int st = 1; st < 64; st <<= 1) {
                const float nm = __shfl_down(inc, st);
                if (lane + st < 64) inc += nm;
            }
            float xofs = __shfl_down(inc, 1);
            if (lane == 63) xofs = 0.f;
            if (lane == 0) wss[w] = inc;
            __syncthreads();   // B3
            #pragma unroll
            for (int ww = 1; ww < 4; ++ww)
                if (ww > w) xofs += wss[ww];
            #pragma unroll
            for (int jj = 0; jj < 8; ++jj) Sf[cb + jj] = sx[jj] + xofs;
            if (t == 0) Sf[NN] = 0.f;
        }
        __syncthreads();   // B4: Pf/Sf(A) ready
        const float MBA = MA - CS;
        #pragma unroll
        for (int jj = 0; jj < 8; ++jj) {
            const int p = cb + jj;
            if (p == rA) continue;
            const float s = fmaxf(Pf[L8[jj]] + Sf[R8[jj]], 1e-38f);
            lnsumA += (double)(MBA + __logf(s));
        }
    }
    __syncthreads();   // B5: done reading Pf/Sf(A)

    // ================= row B: scans + accumulate =================
    double lnsumB = 0.0;
    {
        float e8[8];
        #pragma unroll
        for (int jj = 0; jj < 8; ++jj) e8[jj] = __expf(vB[jj] - MB + CS);
        {
            float run = 0.f, ex[8];
            #pragma unroll
            for (int jj = 0; jj < 8; ++jj) { ex[jj] = run; run += e8[jj]; }
            float inc = run;
            #pragma unroll
            for (int st = 1; st < 64; st <<= 1) {
                const float nm = __shfl_up(inc, st);
                if (lane >= st) inc += nm;
            }
            float xofs = __shfl_up(inc, 1);
            if (lane == 0) xofs = 0.f;
            if (lane == 63) wps[w] = inc;
            __syncthreads();   // B6
            #pragma unroll
            for (int ww = 0; ww < 3; ++ww)
                if (ww < w) xofs += wps[ww];
            #pragma unroll
            for (int jj = 0; jj < 8; ++jj) Pf[cb + jj] = ex[jj] + xofs;
        }
        {
            float run = 0.f, sx[8];
            #pragma unroll
            for (int jj = 7; jj >= 0; --jj) { run += e8[jj]; sx[jj] = run; }
            float inc = run;
            #pragma unroll
            for (int st = 1; st < 64; st <<= 1) {
                const float nm = __shfl_down(inc, st);
                if (lane + st < 64) inc += nm;
            }
            float xofs = __shfl_down(inc, 1);
            if (lane == 63) xofs = 0.f;
            if (lane == 0) wss[w] = inc;
            __syncthreads();   // B7
            #pragma unroll
            for (int ww = 1; ww < 4; ++ww)
                if (ww > w) xofs += wss[ww];
            #pragma unroll
            for (int jj = 0; jj < 8; ++jj) Sf[cb + jj] = sx[jj] + xofs;
            if (t == 0) Sf[NN] = 0.f;
        }
        __syncthreads();   // B8: Pf/Sf(B) ready
        const float MBB = MB - CS;
        #pragma unroll
        for (int jj = 0; jj < 8; ++jj) {
            const int p = cb + jj;
            if (p == rB) continue;
            const float s = fmaxf(Pf[L8[jj]] + Sf[R8[jj]], 1e-38f);
            lnsumB += (double)(MBB + __logf(s));
        }
    }

    // ---- reductions (both rows) ----
    #pragma unroll
    for (int st = 32; st > 0; st >>= 1) {
        dsumA  += __shfl_down(dsumA, st);
        lnsumA += __shfl_down(lnsumA, st);
        dsumB  += __shfl_down(dsumB, st);
        lnsumB += __shfl_down(lnsumB, st);
    }
    if (lane == 0) { wDA[w] = dsumA; wLA[w] = lnsumA; wDB[w] = dsumB; wLB[w] = lnsumB; }
    __syncthreads();   // B9
    if (t == 0) {
        rowval[rA] = (-(wDA[0] + wDA[1] + wDA[2] + wDA[3]) / 0.07)
                   - (wLA[0] + wLA[1] + wLA[2] + wLA[3]);
        rowval[rB] = (-(wDB[0] + wDB[1] + wDB[2] + wDB[3]) / 0.07)
                   - (wLB[0] + wLB[1] + wLB[2] + wLB[3]);
    }
}

// ---------------- kernel 3: final mean ----------------
__global__ __launch_bounds__(256) void finalize_kernel(const double* __restrict__ rowval,
                                                       float* __restrict__ out) {
    __shared__ double red[NT];
    const int t = threadIdx.x;
    double s = 0.0;
    for (int j = t; j < NN; j += NT) s += rowval[j];
    red[t] = s;
    __syncthreads();
    for (int ofs = NT / 2; ofs > 0; ofs >>= 1) {
        if (t < ofs) red[t] += red[t + ofs];
        __syncthreads();
    }
    if (t == 0) {
        out[0] = (float)(-red[0] / ((double)NN * (double)(NN - 1)));
    }
}

extern "C" void kernel_launch(void* const* d_in, const int* in_sizes, int n_in,
                              void* d_out, int out_size, void* d_ws, size_t ws_size,
                              hipStream_t stream) {
    const float* features = (const float*)d_in[0];  // [1024, 2, 512] fp32
    const float* labels   = (const float*)d_in[1];  // [1024] fp32
    float* out = (float*)d_out;

    char* ws = (char*)d_ws;
    size_t off = 0;
    float*  sq     = (float*) (ws + off); off += NN * sizeof(float);
    float*  slab   = (float*) (ws + off); off += NN * sizeof(float);
    int*    sj     = (int*)   (ws + off); off += NN * sizeof(int);
    double* rowval = (double*)(ws + off); off += NN * sizeof(double);
    ushort* Ahi    = (ushort*)(ws + off); off += (size_t)NN * DD * sizeof(ushort);
    ushort* Alo    = (ushort*)(ws + off); off += (size_t)NN * DD * sizeof(ushort);
    float*  distp  = (float*) (ws + off); off += (size_t)NN * NN * sizeof(float);

    prep_sort_kernel<<<258, 512, 0, stream>>>(features, labels, Ahi, Alo, sq, slab, sj);
    gemm_dist_kernel<<<16 * 17, NT, 0, stream>>>(Ahi, Alo, sq, sj, distp);  // 272 lower tiles
    row_kernel<<<NN / 2, NT, 0, stream>>>(distp, slab, rowval);
    finalize_kernel<<<1, NT, 0, stream>>>(rowval, out);
}